// Round 6
// baseline (445.216 us; speedup 1.0000x reference)
//
#include <hip/hip_runtime.h>
#include <stdint.h>

typedef unsigned short u16;
typedef __attribute__((ext_vector_type(8))) __bf16 bf8v;    // A/B fragment: 8 bf16
typedef __attribute__((ext_vector_type(4))) float f4v;      // 16x16 C/D
typedef __attribute__((ext_vector_type(16))) float f16v;    // 32x32 C/D

#define BB 2
#define SS 2048
#define HH 1024

// workspace layout (bytes) — extent 56688640 == round-3 extent (proven harmless).
#define OFF_Q   0u          // Q bf16 [4096][1024]; later attn output (same region)
#define OFF_K0  8388608u
#define OFF_K1  16777216u
#define OFF_K2  20971520u
#define OFF_K3  23068672u
#define OFF_V0  24117248u
#define OFF_V1  32505856u
#define OFF_V2  36700160u
#define OFF_V3  38797312u
#define OFF_WQT 39845888u   // Wqkv^T bf16 [3072][1024]  (6 MB)
#define OFF_WOT 46137344u   // Wout^T bf16 [1024][1024]  (2 MB)
#define OFF_XB  48234496u   // x bf16 [4096][1024]       (8 MB)
#define OFF_SCW 56623104u   // scale weights f32 [4096][4] (64 KB) -> ends 56688640

__device__ __forceinline__ u16 f2bf(float f) {
    union { float f; uint32_t u; } v; v.f = f;
    uint32_t r = v.u + 0x7fffu + ((v.u >> 16) & 1u);   // RNE
    return (u16)(r >> 16);
}
__device__ __forceinline__ uint32_t pk2(float a, float b) {
    return (uint32_t)f2bf(a) | ((uint32_t)f2bf(b) << 16);
}
// truncation pack (2 VALU): low half <- bf-trunc(a), high half <- bf-trunc(b)
__device__ __forceinline__ uint32_t pkt2(float a, float b) {
    union { float f; uint32_t u; } x, y; x.f = a; y.f = b;
    return (x.u >> 16) | (y.u & 0xffff0000u);
}

// ---------------- x f32 -> bf16 ----------------
__global__ __launch_bounds__(256) void xconv_kernel(const float* __restrict__ x,
                                                    u16* __restrict__ xb) {
    size_t t = (size_t)blockIdx.x * 256 + threadIdx.x;
    float4 v = *(const float4*)&x[t * 4];
    uint2 pk; pk.x = pk2(v.x, v.y); pk.y = pk2(v.z, v.w);
    *(uint2*)&xb[t * 4] = pk;
}

// ---------------- W f32 [K][N] -> bf16 W^T [N][K] ----------------
__global__ __launch_bounds__(256) void wconv_kernel(const float* __restrict__ W,
                                                    u16* __restrict__ Wt,
                                                    int N, int K) {
    __shared__ float tile[64][69];
    const int tid = threadIdx.x;
    const int n0 = blockIdx.x * 64, k0 = blockIdx.y * 64;
    const int r = tid >> 4, c4 = (tid & 15) * 4;
#pragma unroll
    for (int it = 0; it < 4; it++) {
        float4 v = *(const float4*)&W[(size_t)(k0 + it * 16 + r) * N + n0 + c4];
        tile[it * 16 + r][c4 + 0] = v.x; tile[it * 16 + r][c4 + 1] = v.y;
        tile[it * 16 + r][c4 + 2] = v.z; tile[it * 16 + r][c4 + 3] = v.w;
    }
    __syncthreads();
#pragma unroll
    for (int it = 0; it < 4; it++) {
        int n = it * 16 + r;
        uint2 pk;
        pk.x = pk2(tile[c4 + 0][n], tile[c4 + 1][n]);
        pk.y = pk2(tile[c4 + 2][n], tile[c4 + 3][n]);
        *(uint2*)&Wt[(size_t)(n0 + n) * K + k0 + c4] = pk;
    }
}

// ---------------- scale weights: softmax(x @ Wscale + bscale) ----------------
__global__ __launch_bounds__(256) void scale_kernel(const float* __restrict__ x,
                                                    const float* __restrict__ Wscale,
                                                    const float* __restrict__ bscale,
                                                    float* __restrict__ scw) {
    const int lane = threadIdx.x & 63;
    const int wid  = threadIdx.x >> 6;
    const int row  = blockIdx.x * 4 + wid;
    float a0 = 0.f, a1 = 0.f, a2 = 0.f, a3 = 0.f;
    for (int i = 0; i < 16; i++) {
        int hh = lane + i * 64;
        float xs = x[(size_t)row * HH + hh];
        float4 wv = *(const float4*)&Wscale[hh * 4];
        a0 += xs * wv.x; a1 += xs * wv.y; a2 += xs * wv.z; a3 += xs * wv.w;
    }
    for (int off = 1; off < 64; off <<= 1) {
        a0 += __shfl_xor(a0, off); a1 += __shfl_xor(a1, off);
        a2 += __shfl_xor(a2, off); a3 += __shfl_xor(a3, off);
    }
    if (lane == 0) {
        a0 += bscale[0]; a1 += bscale[1]; a2 += bscale[2]; a3 += bscale[3];
        float mx = fmaxf(fmaxf(a0, a1), fmaxf(a2, a3));
        float e0 = __expf(a0 - mx), e1 = __expf(a1 - mx);
        float e2 = __expf(a2 - mx), e3 = __expf(a3 - mx);
        float inv = 1.f / (e0 + e1 + e2 + e3);
        float4 o = {e0 * inv, e1 * inv, e2 * inv, e3 * inv};
        *(float4*)&scw[(size_t)row * 4] = o;
    }
}

// ---------------- bf16 MFMA GEMM, A bf16, B pre-transposed bf16 ----------------
// MODE 0: C[M,N] f32 = A@B + bias.  MODE 1: QKV scatter epilogue (K scaled by 0.125).
template<int MODE>
__global__ __launch_bounds__(256) void gemm_bt(const u16* __restrict__ A,
                                               const u16* __restrict__ Bt,
                                               const float* __restrict__ bias,
                                               void* __restrict__ Cp,
                                               int N, int K) {
    __shared__ __align__(16) u16 At[128 * 40];
    __shared__ __align__(16) u16 Btl[128 * 40];
    const int tid  = threadIdx.x;
    const int lane = tid & 63;
    const int wid  = tid >> 6;
    const int l15  = lane & 15;
    const int quad = lane >> 4;
    const int wm = wid & 1, wn = wid >> 1;
    const int m0 = blockIdx.y * 128;
    const int n0 = blockIdx.x * 128;
    const int srow = tid >> 2;           // 0..63
    const int sc8  = (tid & 3) * 8;      // 0,8,16,24

    f4v acc[4][4];
#pragma unroll
    for (int i = 0; i < 4; i++)
#pragma unroll
        for (int j = 0; j < 4; j++) acc[i][j] = (f4v){0.f, 0.f, 0.f, 0.f};

    uint4 pa0 = *(const uint4*)(A  + (size_t)(m0 + srow) * K + sc8);
    uint4 pa1 = *(const uint4*)(A  + (size_t)(m0 + srow + 64) * K + sc8);
    uint4 pb0 = *(const uint4*)(Bt + (size_t)(n0 + srow) * K + sc8);
    uint4 pb1 = *(const uint4*)(Bt + (size_t)(n0 + srow + 64) * K + sc8);

    for (int kc = 0; kc < K; kc += 32) {
        __syncthreads();
        *(uint4*)&At[srow * 40 + sc8]         = pa0;
        *(uint4*)&At[(srow + 64) * 40 + sc8]  = pa1;
        *(uint4*)&Btl[srow * 40 + sc8]        = pb0;
        *(uint4*)&Btl[(srow + 64) * 40 + sc8] = pb1;
        __syncthreads();
        if (kc + 32 < K) {
            pa0 = *(const uint4*)(A  + (size_t)(m0 + srow) * K + kc + 32 + sc8);
            pa1 = *(const uint4*)(A  + (size_t)(m0 + srow + 64) * K + kc + 32 + sc8);
            pb0 = *(const uint4*)(Bt + (size_t)(n0 + srow) * K + kc + 32 + sc8);
            pb1 = *(const uint4*)(Bt + (size_t)(n0 + srow + 64) * K + kc + 32 + sc8);
        }
        bf8v af[4], bf[4];
#pragma unroll
        for (int t = 0; t < 4; t++) {
            af[t] = *(const bf8v*)&At[(wm * 64 + t * 16 + l15) * 40 + quad * 8];
            bf[t] = *(const bf8v*)&Btl[(wn * 64 + t * 16 + l15) * 40 + quad * 8];
        }
#pragma unroll
        for (int ti = 0; ti < 4; ti++)
#pragma unroll
            for (int tj = 0; tj < 4; tj++)
                acc[ti][tj] = __builtin_amdgcn_mfma_f32_16x16x32_bf16(af[ti], bf[tj], acc[ti][tj], 0, 0, 0);
    }

    if (MODE == 0) {
#pragma unroll
        for (int ti = 0; ti < 4; ti++)
#pragma unroll
            for (int tj = 0; tj < 4; tj++)
#pragma unroll
                for (int r = 0; r < 4; r++) {
                    int m = m0 + wm * 64 + ti * 16 + quad * 4 + r;
                    int n = n0 + wn * 64 + tj * 16 + l15;
                    ((float*)Cp)[(size_t)m * N + n] = acc[ti][tj][r] + bias[n];
                }
    } else {
        char* ws = (char*)Cp;
        u16* Qd = (u16*)ws;
        u16* K0 = (u16*)(ws + OFF_K0); u16* K1 = (u16*)(ws + OFF_K1);
        u16* K2 = (u16*)(ws + OFF_K2); u16* K3 = (u16*)(ws + OFF_K3);
        u16* V0 = (u16*)(ws + OFF_V0); u16* V1 = (u16*)(ws + OFF_V1);
        u16* V2 = (u16*)(ws + OFF_V2); u16* V3 = (u16*)(ws + OFF_V3);
        const int region = n0 >> 10;
        if (region == 0) {             // ---- Q dense bf16 [tok][h*64+hd]
#pragma unroll
            for (int ti = 0; ti < 4; ti++)
#pragma unroll
                for (int tj = 0; tj < 4; tj++)
#pragma unroll
                    for (int r = 0; r < 4; r++) {
                        int m = m0 + wm * 64 + ti * 16 + quad * 4 + r;
                        int n = n0 + wn * 64 + tj * 16 + l15;
                        Qd[(size_t)m * 1024 + n] = f2bf(acc[ti][tj][r] + bias[n]);
                    }
        } else if (region == 1) {      // ---- K dilated copies, scaled by 1/sqrt(64)
#pragma unroll
            for (int ti = 0; ti < 4; ti++)
#pragma unroll
                for (int tj = 0; tj < 4; tj++) {
                    int n  = n0 + wn * 64 + tj * 16 + l15;
                    int nk = n - 1024;
                    int h = nk >> 6, hd = nk & 63;
#pragma unroll
                    for (int r = 0; r < 4; r++) {
                        int m = m0 + wm * 64 + ti * 16 + quad * 4 + r;
                        int bb = m >> 11, tok = m & 2047;
                        int bh = bb * 16 + h;
                        u16 bv = f2bf((acc[ti][tj][r] + bias[n]) * 0.125f);
                        K0[((size_t)bh * 2048 + tok) * 64 + hd] = bv;
                        if (!(r & 1)) K1[((size_t)bh * 1024 + (tok >> 1)) * 64 + hd] = bv;
                        if (r == 0) {
                            K2[((size_t)bh * 512 + (tok >> 2)) * 64 + hd] = bv;
                            if (!(quad & 1)) K3[((size_t)bh * 256 + (tok >> 3)) * 64 + hd] = bv;
                        }
                    }
                }
        } else {                       // ---- V^T dilated copies [b,h,hd,tok]
#pragma unroll
            for (int ti = 0; ti < 4; ti++)
#pragma unroll
                for (int tj = 0; tj < 4; tj++) {
                    int n  = n0 + wn * 64 + tj * 16 + l15;
                    int nv = n - 2048;
                    int h = nv >> 6, hd = nv & 63;
                    int tokb = m0 + wm * 64 + ti * 16 + quad * 4;
                    int bb = tokb >> 11, tok = tokb & 2047;
                    int bh = bb * 16 + h;
                    float v0 = acc[ti][tj][0] + bias[n];
                    float v1 = acc[ti][tj][1] + bias[n];
                    float v2 = acc[ti][tj][2] + bias[n];
                    float v3 = acc[ti][tj][3] + bias[n];
                    u16 c0 = f2bf(v0), c1 = f2bf(v1), c2 = f2bf(v2), c3 = f2bf(v3);
                    uint2 pk;
                    pk.x = (uint32_t)c0 | ((uint32_t)c1 << 16);
                    pk.y = (uint32_t)c2 | ((uint32_t)c3 << 16);
                    *(uint2*)&V0[((size_t)bh * 64 + hd) * 2048 + tok] = pk;
                    *(uint32_t*)&V1[((size_t)bh * 64 + hd) * 1024 + (tok >> 1)] =
                        (uint32_t)c0 | ((uint32_t)c2 << 16);
                    V2[((size_t)bh * 64 + hd) * 512 + (tok >> 2)] = c0;
                    if (!(quad & 1)) V3[((size_t)bh * 64 + hd) * 256 + (tok >> 3)] = c0;
                }
        }
    }
}

// ---------------- multi-scale attention, 32x32x16 MFMA, scale-split waves ----------------
// block = 64 q, 2 waves: wave0 computes scale 0 (64 chunks), wave1 scales 1-3 (56 chunks).
// Each wave stages K/V privately -> NO __syncthreads in the hot loop (in-wave DS ordering
// + explicit lgkmcnt waits). Partials combined once per block through an LDS union.
// Dataflow per wave (round-5 verified): S^T = K.Q^T (col=q=l31), P [q][key] in LDS,
// O^T = V.P^T (col=q=l31).
#define WLDS 14848   // per-wave: Kt 4608 + Vt 5120 + Pt 5120
__global__ __launch_bounds__(128, 2) void attn_kernel(const char* __restrict__ ws) {
    __shared__ __align__(16) char smem[2 * WLDS];   // also unioned as 16KB combine buf

    const u16* Qd    = (const u16*)(ws + OFF_Q);
    const float* scw = (const float*)(ws + OFF_SCW);
    u16* attnb       = (u16*)(ws + OFF_Q);          // aliases Q (block reads Q first)

    const int tid  = threadIdx.x;
    const int lane = tid & 63;
    const int wid  = tid >> 6;
    const int l31  = lane & 31;
    const int half = lane >> 5;
    const int b = blockIdx.z, h = blockIdx.y;
    const int qb = blockIdx.x * 64;
    const int bh = b * 16 + h;

    u16* Kt = (u16*)(smem + wid * WLDS);            // [key][hd] pad 72 rows (32x72)
    u16* Vt = (u16*)(smem + wid * WLDS + 9216);     // [hd][key] pad 40 rows (64x40)
    u16* Pw = (u16*)(smem + wid * WLDS + 9216 + 5120 ? 0 : 0, smem + wid * WLDS + 4608);
    // NOTE: layout: Kt [0,4608), Pw... fix below
    Kt = (u16*)(smem + wid * WLDS);
    u16* Vt2 = (u16*)(smem + wid * WLDS + 4608);
    u16* Pw2 = (u16*)(smem + wid * WLDS + 9728);
    float* comb = (float*)smem;

    // staging lane coords (coalesced 1KB per instr)
    const int skey = lane >> 3;           // + i*8  -> key row
    const int sgr  = lane & 7;            // 16B granule in K row
    const int svr  = lane >> 2;           // + i*16 -> hd row
    const int skg  = lane & 3;            // 16B granule in V row

    // Q B-frags: qf[qt][ks] = Q[qb+qt*32+l31][ks*16 + half*8 + j]
    bf8v qf[2][4];
#pragma unroll
    for (int qt = 0; qt < 2; qt++)
#pragma unroll
        for (int ks = 0; ks < 4; ks++)
            qf[qt][ks] = *(const bf8v*)(Qd + (size_t)(b * SS + qb + qt * 32 + l31) * 1024
                                        + h * 64 + ks * 16 + half * 8);

    f16v ofin[2][2];
#pragma unroll
    for (int qt = 0; qt < 2; qt++)
#pragma unroll
        for (int ht = 0; ht < 2; ht++)
#pragma unroll
            for (int r = 0; r < 16; r++) ofin[qt][ht][r] = 0.f;

    const uint32_t koff[4] = {OFF_K0, OFF_K1, OFF_K2, OFF_K3};
    const uint32_t voff[4] = {OFF_V0, OFF_V1, OFF_V2, OFF_V3};
    const int s_lo = wid ? 1 : 0;
    const int s_hi = wid ? 3 : 0;

    for (int s = s_lo; s <= s_hi; s++) {
        const int Ss = SS >> s;
        const int nch = Ss >> 5;
        const u16* Kb = (const u16*)(ws + koff[s]) + (size_t)bh * Ss * 64;
        const u16* Vb = (const u16*)(ws + voff[s]) + (size_t)bh * 64 * Ss;

        f16v oacc[2][2];
#pragma unroll
        for (int qt = 0; qt < 2; qt++)
#pragma unroll
            for (int ht = 0; ht < 2; ht++)
#pragma unroll
                for (int r = 0; r < 16; r++) oacc[qt][ht][r] = 0.f;
        float ls0 = 0.f, ls1 = 0.f;

        uint4 kr[4];
#pragma unroll
        for (int i = 0; i < 4; i++)
            kr[i] = *(const uint4*)(Kb + (size_t)(i * 8 + skey) * 64 + sgr * 8);

        for (int c = 0; c < nch; c++) {
            // V loads for this chunk (latency overlapped with K staging + QK + softmax)
            uint4 vr[4];
#pragma unroll
            for (int i = 0; i < 4; i++)
                vr[i] = *(const uint4*)(Vb + (size_t)(i * 16 + svr) * Ss + c * 32 + skg * 8);
            // stage K (held in kr)
#pragma unroll
            for (int i = 0; i < 4; i++)
                *(uint4*)&Kt[(i * 8 + skey) * 72 + sgr * 8] = kr[i];
            // prefetch next chunk's K
            if (c + 1 < nch) {
#pragma unroll
                for (int i = 0; i < 4; i++)
                    kr[i] = *(const uint4*)(Kb + (size_t)((c + 1) * 32 + i * 8 + skey) * 64 + sgr * 8);
            }
            __asm__ volatile("s_waitcnt lgkmcnt(0)" ::: "memory");
            // ---- QK: S^T col=q(l31), rows=key
            f16v sa0, sa1;
#pragma unroll
            for (int r = 0; r < 16; r++) { sa0[r] = 0.f; sa1[r] = 0.f; }
#pragma unroll
            for (int ks = 0; ks < 4; ks++) {
                bf8v ka = *(const bf8v*)&Kt[l31 * 72 + ks * 16 + half * 8];
                sa0 = __builtin_amdgcn_mfma_f32_32x32x16_bf16(ka, qf[0][ks], sa0, 0, 0, 0);
                sa1 = __builtin_amdgcn_mfma_f32_32x32x16_bf16(ka, qf[1][ks], sa1, 0, 0, 0);
            }
            // ---- exp + truncation-pack + P write; reg r=g*4+i -> key g*8+half*4+i
#pragma unroll
            for (int qt = 0; qt < 2; qt++) {
                const f16v& sa = qt ? sa1 : sa0;
                float lq = 0.f;
#pragma unroll
                for (int g = 0; g < 4; g++) {
                    float e0 = __expf(sa[g * 4 + 0]);
                    float e1 = __expf(sa[g * 4 + 1]);
                    float e2 = __expf(sa[g * 4 + 2]);
                    float e3 = __expf(sa[g * 4 + 3]);
                    lq += (e0 + e1) + (e2 + e3);
                    uint2 pk;
                    pk.x = pkt2(e0, e1);
                    pk.y = pkt2(e2, e3);
                    *(uint2*)&Pw2[(qt * 32 + l31) * 40 + g * 8 + half * 4] = pk;
                }
                if (qt) ls1 += lq; else ls0 += lq;
            }
            // stage V (vmcnt wait folded here by compiler)
#pragma unroll
            for (int i = 0; i < 4; i++)
                *(uint4*)&Vt2[(i * 16 + svr) * 40 + skg * 8] = vr[i];
            __asm__ volatile("s_waitcnt lgkmcnt(0)" ::: "memory");
            // ---- PV: O^T col=q(l31), rows=hd
#pragma unroll
            for (int kst = 0; kst < 2; kst++) {
                bf8v pb0 = *(const bf8v*)&Pw2[l31 * 40 + kst * 16 + half * 8];
                bf8v pb1 = *(const bf8v*)&Pw2[(32 + l31) * 40 + kst * 16 + half * 8];
#pragma unroll
                for (int ht = 0; ht < 2; ht++) {
                    bf8v va = *(const bf8v*)&Vt2[(ht * 32 + l31) * 40 + kst * 16 + half * 8];
                    oacc[0][ht] = __builtin_amdgcn_mfma_f32_32x32x16_bf16(va, pb0, oacc[0][ht], 0, 0, 0);
                    oacc[1][ht] = __builtin_amdgcn_mfma_f32_32x32x16_bf16(va, pb1, oacc[1][ht], 0, 0, 0);
                }
            }
        }
        // ---- fold scale s (per-lane q=l31, consistent with col=q orientation)
#pragma unroll
        for (int qt = 0; qt < 2; qt++) {
            float l = qt ? ls1 : ls0;
            l += __shfl_xor(l, 32);
            float w = scw[(size_t)(b * SS + qb + qt * 32 + l31) * 4 + s] / l;
#pragma unroll
            for (int ht = 0; ht < 2; ht++)
#pragma unroll
                for (int r = 0; r < 16; r++) ofin[qt][ht][r] += w * oacc[qt][ht][r];
        }
    }

    // ---- combine wave1's partial into wave0's, write O
    __syncthreads();
    if (wid == 1) {
#pragma unroll
        for (int qt = 0; qt < 2; qt++)
#pragma unroll
            for (int ht = 0; ht < 2; ht++)
#pragma unroll
                for (int g = 0; g < 4; g++) {
                    int slot = qt * 8 + ht * 4 + g;
                    float4 v = {ofin[qt][ht][g * 4 + 0], ofin[qt][ht][g * 4 + 1],
                                ofin[qt][ht][g * 4 + 2], ofin[qt][ht][g * 4 + 3]};
                    *(float4*)&comb[slot * 256 + lane * 4] = v;
                }
    }
    __syncthreads();
    if (wid == 0) {
#pragma unroll
        for (int qt = 0; qt < 2; qt++) {
            const size_t base = (size_t)(b * SS + qb + qt * 32 + l31) * 1024 + h * 64;
#pragma unroll
            for (int ht = 0; ht < 2; ht++)
#pragma unroll
                for (int g = 0; g < 4; g++) {
                    int slot = qt * 8 + ht * 4 + g;
                    float4 v = *(const float4*)&comb[slot * 256 + lane * 4];
                    float o0 = ofin[qt][ht][g * 4 + 0] + v.x;
                    float o1 = ofin[qt][ht][g * 4 + 1] + v.y;
                    float o2 = ofin[qt][ht][g * 4 + 2] + v.z;
                    float o3 = ofin[qt][ht][g * 4 + 3] + v.w;
                    uint2 pk;
                    pk.x = pk2(o0, o1);
                    pk.y = pk2(o2, o3);
                    *(uint2*)&attnb[base + ht * 32 + g * 8 + half * 4] = pk;
                }
        }
    }
}

extern "C" void kernel_launch(void* const* d_in, const int* in_sizes, int n_in,
                              void* d_out, int out_size, void* d_ws, size_t ws_size,
                              hipStream_t stream) {
    const float* x      = (const float*)d_in[0];
    const float* Wqkv   = (const float*)d_in[1];
    const float* bqkv   = (const float*)d_in[2];
    const float* Wout   = (const float*)d_in[3];
    const float* bout   = (const float*)d_in[4];
    const float* Wscale = (const float*)d_in[5];
    const float* bscale = (const float*)d_in[6];
    float* out = (float*)d_out;

    char* ws = (char*)d_ws;
    u16*   wqt   = (u16*)(ws + OFF_WQT);
    u16*   wot   = (u16*)(ws + OFF_WOT);
    u16*   xb    = (u16*)(ws + OFF_XB);
    u16*   attnb = (u16*)(ws + OFF_Q);
    float* scw   = (float*)(ws + OFF_SCW);

    xconv_kernel<<<dim3(4096), dim3(256), 0, stream>>>(x, xb);
    wconv_kernel<<<dim3(48, 16), dim3(256), 0, stream>>>(Wqkv, wqt, 3072, 1024);
    wconv_kernel<<<dim3(16, 16), dim3(256), 0, stream>>>(Wout, wot, 1024, 1024);
    scale_kernel<<<dim3(1024), dim3(256), 0, stream>>>(x, Wscale, bscale, scw);
    gemm_bt<1><<<dim3(24, 32), dim3(256), 0, stream>>>(xb, wqt, bqkv, (void*)ws, 3072, 1024);
    attn_kernel<<<dim3(32, 16, 2), dim3(128), 0, stream>>>(ws);
    gemm_bt<0><<<dim3(8, 32), dim3(256), 0, stream>>>(attnb, wot, bout, (void*)out, 1024, 1024);
}

// Round 7
// 297.188 us; speedup vs baseline: 1.4981x; 1.4981x over previous
//
#include <hip/hip_runtime.h>
#include <stdint.h>

typedef unsigned short u16;
typedef __attribute__((ext_vector_type(8))) __bf16 bf8v;    // A/B fragment: 8 bf16
typedef __attribute__((ext_vector_type(4))) float f4v;      // 16x16 C/D
typedef __attribute__((ext_vector_type(16))) float f16v;    // 32x32 C/D

#define BB 2
#define SS 2048
#define HH 1024

// workspace layout (bytes) — extent 56688640 (proven harmless in rounds 3/4/6).
#define OFF_Q   0u          // Q bf16 [4096][1024]; later attn output (same region)
#define OFF_K0  8388608u
#define OFF_K1  16777216u
#define OFF_K2  20971520u
#define OFF_K3  23068672u
#define OFF_V0  24117248u
#define OFF_V1  32505856u
#define OFF_V2  36700160u
#define OFF_V3  38797312u
#define OFF_WQT 39845888u   // Wqkv^T bf16 [3072][1024]  (6 MB)
#define OFF_WOT 46137344u   // Wout^T bf16 [1024][1024]  (2 MB)
#define OFF_XB  48234496u   // x bf16 [4096][1024]       (8 MB)
#define OFF_SCW 56623104u   // scale weights f32 [4096][4] (64 KB)

__device__ __forceinline__ u16 f2bf(float f) {
    union { float f; uint32_t u; } v; v.f = f;
    uint32_t r = v.u + 0x7fffu + ((v.u >> 16) & 1u);   // RNE
    return (u16)(r >> 16);
}
__device__ __forceinline__ uint32_t pk2(float a, float b) {
    return (uint32_t)f2bf(a) | ((uint32_t)f2bf(b) << 16);
}
// truncation pack (2 VALU): low half <- bf-trunc(a), high half <- bf-trunc(b)
__device__ __forceinline__ uint32_t pkt2(float a, float b) {
    union { float f; uint32_t u; } x, y; x.f = a; y.f = b;
    return (x.u >> 16) | (y.u & 0xffff0000u);
}

// ---------------- x f32 -> bf16 ----------------
__global__ __launch_bounds__(256) void xconv_kernel(const float* __restrict__ x,
                                                    u16* __restrict__ xb) {
    size_t t = (size_t)blockIdx.x * 256 + threadIdx.x;
    float4 v = *(const float4*)&x[t * 4];
    uint2 pk; pk.x = pk2(v.x, v.y); pk.y = pk2(v.z, v.w);
    *(uint2*)&xb[t * 4] = pk;
}

// ---------------- W f32 [K][N] -> bf16 W^T [N][K] ----------------
__global__ __launch_bounds__(256) void wconv_kernel(const float* __restrict__ W,
                                                    u16* __restrict__ Wt,
                                                    int N, int K) {
    __shared__ float tile[64][69];
    const int tid = threadIdx.x;
    const int n0 = blockIdx.x * 64, k0 = blockIdx.y * 64;
    const int r = tid >> 4, c4 = (tid & 15) * 4;
#pragma unroll
    for (int it = 0; it < 4; it++) {
        float4 v = *(const float4*)&W[(size_t)(k0 + it * 16 + r) * N + n0 + c4];
        tile[it * 16 + r][c4 + 0] = v.x; tile[it * 16 + r][c4 + 1] = v.y;
        tile[it * 16 + r][c4 + 2] = v.z; tile[it * 16 + r][c4 + 3] = v.w;
    }
    __syncthreads();
#pragma unroll
    for (int it = 0; it < 4; it++) {
        int n = it * 16 + r;
        uint2 pk;
        pk.x = pk2(tile[c4 + 0][n], tile[c4 + 1][n]);
        pk.y = pk2(tile[c4 + 2][n], tile[c4 + 3][n]);
        *(uint2*)&Wt[(size_t)(n0 + n) * K + k0 + c4] = pk;
    }
}

// ---------------- scale weights: softmax(x @ Wscale + bscale) ----------------
__global__ __launch_bounds__(256) void scale_kernel(const float* __restrict__ x,
                                                    const float* __restrict__ Wscale,
                                                    const float* __restrict__ bscale,
                                                    float* __restrict__ scw) {
    const int lane = threadIdx.x & 63;
    const int wid  = threadIdx.x >> 6;
    const int row  = blockIdx.x * 4 + wid;
    float a0 = 0.f, a1 = 0.f, a2 = 0.f, a3 = 0.f;
    for (int i = 0; i < 16; i++) {
        int hh = lane + i * 64;
        float xs = x[(size_t)row * HH + hh];
        float4 wv = *(const float4*)&Wscale[hh * 4];
        a0 += xs * wv.x; a1 += xs * wv.y; a2 += xs * wv.z; a3 += xs * wv.w;
    }
    for (int off = 1; off < 64; off <<= 1) {
        a0 += __shfl_xor(a0, off); a1 += __shfl_xor(a1, off);
        a2 += __shfl_xor(a2, off); a3 += __shfl_xor(a3, off);
    }
    if (lane == 0) {
        a0 += bscale[0]; a1 += bscale[1]; a2 += bscale[2]; a3 += bscale[3];
        float mx = fmaxf(fmaxf(a0, a1), fmaxf(a2, a3));
        float e0 = __expf(a0 - mx), e1 = __expf(a1 - mx);
        float e2 = __expf(a2 - mx), e3 = __expf(a3 - mx);
        float inv = 1.f / (e0 + e1 + e2 + e3);
        float4 o = {e0 * inv, e1 * inv, e2 * inv, e3 * inv};
        *(float4*)&scw[(size_t)row * 4] = o;
    }
}

// ---------------- bf16 MFMA GEMM, A bf16, B pre-transposed bf16 ----------------
// MODE 0: C[M,N] f32 = A@B + bias.  MODE 1: QKV scatter epilogue (K scaled by 0.125).
template<int MODE>
__global__ __launch_bounds__(256) void gemm_bt(const u16* __restrict__ A,
                                               const u16* __restrict__ Bt,
                                               const float* __restrict__ bias,
                                               void* __restrict__ Cp,
                                               int N, int K) {
    __shared__ __align__(16) u16 At[128 * 40];
    __shared__ __align__(16) u16 Btl[128 * 40];
    const int tid  = threadIdx.x;
    const int lane = tid & 63;
    const int wid  = tid >> 6;
    const int l15  = lane & 15;
    const int quad = lane >> 4;
    const int wm = wid & 1, wn = wid >> 1;
    const int m0 = blockIdx.y * 128;
    const int n0 = blockIdx.x * 128;
    const int srow = tid >> 2;           // 0..63
    const int sc8  = (tid & 3) * 8;      // 0,8,16,24

    f4v acc[4][4];
#pragma unroll
    for (int i = 0; i < 4; i++)
#pragma unroll
        for (int j = 0; j < 4; j++) acc[i][j] = (f4v){0.f, 0.f, 0.f, 0.f};

    uint4 pa0 = *(const uint4*)(A  + (size_t)(m0 + srow) * K + sc8);
    uint4 pa1 = *(const uint4*)(A  + (size_t)(m0 + srow + 64) * K + sc8);
    uint4 pb0 = *(const uint4*)(Bt + (size_t)(n0 + srow) * K + sc8);
    uint4 pb1 = *(const uint4*)(Bt + (size_t)(n0 + srow + 64) * K + sc8);

    for (int kc = 0; kc < K; kc += 32) {
        __syncthreads();
        *(uint4*)&At[srow * 40 + sc8]         = pa0;
        *(uint4*)&At[(srow + 64) * 40 + sc8]  = pa1;
        *(uint4*)&Btl[srow * 40 + sc8]        = pb0;
        *(uint4*)&Btl[(srow + 64) * 40 + sc8] = pb1;
        __syncthreads();
        if (kc + 32 < K) {
            pa0 = *(const uint4*)(A  + (size_t)(m0 + srow) * K + kc + 32 + sc8);
            pa1 = *(const uint4*)(A  + (size_t)(m0 + srow + 64) * K + kc + 32 + sc8);
            pb0 = *(const uint4*)(Bt + (size_t)(n0 + srow) * K + kc + 32 + sc8);
            pb1 = *(const uint4*)(Bt + (size_t)(n0 + srow + 64) * K + kc + 32 + sc8);
        }
        bf8v af[4], bf[4];
#pragma unroll
        for (int t = 0; t < 4; t++) {
            af[t] = *(const bf8v*)&At[(wm * 64 + t * 16 + l15) * 40 + quad * 8];
            bf[t] = *(const bf8v*)&Btl[(wn * 64 + t * 16 + l15) * 40 + quad * 8];
        }
#pragma unroll
        for (int ti = 0; ti < 4; ti++)
#pragma unroll
            for (int tj = 0; tj < 4; tj++)
                acc[ti][tj] = __builtin_amdgcn_mfma_f32_16x16x32_bf16(af[ti], bf[tj], acc[ti][tj], 0, 0, 0);
    }

    if (MODE == 0) {
#pragma unroll
        for (int ti = 0; ti < 4; ti++)
#pragma unroll
            for (int tj = 0; tj < 4; tj++)
#pragma unroll
                for (int r = 0; r < 4; r++) {
                    int m = m0 + wm * 64 + ti * 16 + quad * 4 + r;
                    int n = n0 + wn * 64 + tj * 16 + l15;
                    ((float*)Cp)[(size_t)m * N + n] = acc[ti][tj][r] + bias[n];
                }
    } else {
        char* ws = (char*)Cp;
        u16* Qd = (u16*)ws;
        u16* K0 = (u16*)(ws + OFF_K0); u16* K1 = (u16*)(ws + OFF_K1);
        u16* K2 = (u16*)(ws + OFF_K2); u16* K3 = (u16*)(ws + OFF_K3);
        u16* V0 = (u16*)(ws + OFF_V0); u16* V1 = (u16*)(ws + OFF_V1);
        u16* V2 = (u16*)(ws + OFF_V2); u16* V3 = (u16*)(ws + OFF_V3);
        const int region = n0 >> 10;
        if (region == 0) {             // ---- Q dense bf16 [tok][h*64+hd]
#pragma unroll
            for (int ti = 0; ti < 4; ti++)
#pragma unroll
                for (int tj = 0; tj < 4; tj++)
#pragma unroll
                    for (int r = 0; r < 4; r++) {
                        int m = m0 + wm * 64 + ti * 16 + quad * 4 + r;
                        int n = n0 + wn * 64 + tj * 16 + l15;
                        Qd[(size_t)m * 1024 + n] = f2bf(acc[ti][tj][r] + bias[n]);
                    }
        } else if (region == 1) {      // ---- K dilated copies, scaled by 1/sqrt(64)
#pragma unroll
            for (int ti = 0; ti < 4; ti++)
#pragma unroll
                for (int tj = 0; tj < 4; tj++) {
                    int n  = n0 + wn * 64 + tj * 16 + l15;
                    int nk = n - 1024;
                    int h = nk >> 6, hd = nk & 63;
#pragma unroll
                    for (int r = 0; r < 4; r++) {
                        int m = m0 + wm * 64 + ti * 16 + quad * 4 + r;
                        int bb = m >> 11, tok = m & 2047;
                        int bh = bb * 16 + h;
                        u16 bv = f2bf((acc[ti][tj][r] + bias[n]) * 0.125f);
                        K0[((size_t)bh * 2048 + tok) * 64 + hd] = bv;
                        if (!(r & 1)) K1[((size_t)bh * 1024 + (tok >> 1)) * 64 + hd] = bv;
                        if (r == 0) {
                            K2[((size_t)bh * 512 + (tok >> 2)) * 64 + hd] = bv;
                            if (!(quad & 1)) K3[((size_t)bh * 256 + (tok >> 3)) * 64 + hd] = bv;
                        }
                    }
                }
        } else {                       // ---- V^T dilated copies [b,h,hd,tok]
#pragma unroll
            for (int ti = 0; ti < 4; ti++)
#pragma unroll
                for (int tj = 0; tj < 4; tj++) {
                    int n  = n0 + wn * 64 + tj * 16 + l15;
                    int nv = n - 2048;
                    int h = nv >> 6, hd = nv & 63;
                    int tokb = m0 + wm * 64 + ti * 16 + quad * 4;
                    int bb = tokb >> 11, tok = tokb & 2047;
                    int bh = bb * 16 + h;
                    float v0 = acc[ti][tj][0] + bias[n];
                    float v1 = acc[ti][tj][1] + bias[n];
                    float v2 = acc[ti][tj][2] + bias[n];
                    float v3 = acc[ti][tj][3] + bias[n];
                    u16 c0 = f2bf(v0), c1 = f2bf(v1), c2 = f2bf(v2), c3 = f2bf(v3);
                    uint2 pk;
                    pk.x = (uint32_t)c0 | ((uint32_t)c1 << 16);
                    pk.y = (uint32_t)c2 | ((uint32_t)c3 << 16);
                    *(uint2*)&V0[((size_t)bh * 64 + hd) * 2048 + tok] = pk;
                    *(uint32_t*)&V1[((size_t)bh * 64 + hd) * 1024 + (tok >> 1)] =
                        (uint32_t)c0 | ((uint32_t)c2 << 16);
                    V2[((size_t)bh * 64 + hd) * 512 + (tok >> 2)] = c0;
                    if (!(quad & 1)) V3[((size_t)bh * 64 + hd) * 256 + (tok >> 3)] = c0;
                }
        }
    }
}

// ---------------- multi-scale attention, 32x32x16 MFMA, pipelined ----------------
// Round-5 verified math/orientation. block = 128 threads = 2 waves, each wave 64 q.
// K/V staged cooperatively, DOUBLE-BUFFERED: chunk c computes on buf[c&1] while
// buf[1-c&1] is staged for c+1 (regs prefetched during c-1). One barrier per chunk.
// The stage-writes sit between the P LDS write and P LDS read, hiding that latency.
// S^T = K.Q^T (col=q=l31); P [q][key]; O^T = V.P^T (col=q=l31).
__global__ __launch_bounds__(128, 1) void attn_kernel(const char* __restrict__ ws) {
    __shared__ __align__(16) u16 smem[14848];   // Kt 2x2304 | Vt 2x2560 | Pt 2x2560 (u16 elems)
    u16* Kt0 = smem;            // [32 key][72]
    u16* Kt1 = smem + 2304;
    u16* Vt0 = smem + 4608;     // [64 hd][40]
    u16* Vt1 = smem + 7168;
    u16* Pt  = smem + 9728;     // per-wave [64 q][40]

    const u16* Qd    = (const u16*)(ws + OFF_Q);
    const float* scw = (const float*)(ws + OFF_SCW);
    u16* attnb       = (u16*)(ws + OFF_Q);          // aliases Q (block reads Q first)

    const int tid  = threadIdx.x;
    const int lane = tid & 63;
    const int wid  = tid >> 6;
    const int l31  = lane & 31;
    const int half = lane >> 5;
    const int b = blockIdx.z, h = blockIdx.y;
    const int qb = blockIdx.x * 128 + wid * 64;
    const int bh = b * 16 + h;

    // cooperative staging coords (128 threads)
    const int skey = tid >> 3;             // 0..15 (+16 for second half)
    const int shd8 = (tid & 7) * 8;
    const int svhd = tid >> 2;             // 0..31 (+32)
    const int svk8 = (tid & 3) * 8;

    // Q B-frags: qf[qt][ks] = Q[qb+qt*32+l31][ks*16 + half*8 + j]
    bf8v qf[2][4];
#pragma unroll
    for (int qt = 0; qt < 2; qt++)
#pragma unroll
        for (int ks = 0; ks < 4; ks++)
            qf[qt][ks] = *(const bf8v*)(Qd + (size_t)(b * SS + qb + qt * 32 + l31) * 1024
                                        + h * 64 + ks * 16 + half * 8);

    u16* Pw = Pt + wid * 2560;

    f16v ofin[2][2];
#pragma unroll
    for (int qt = 0; qt < 2; qt++)
#pragma unroll
        for (int ht = 0; ht < 2; ht++)
#pragma unroll
            for (int r = 0; r < 16; r++) ofin[qt][ht][r] = 0.f;

    const uint32_t koff[4] = {OFF_K0, OFF_K1, OFF_K2, OFF_K3};
    const uint32_t voff[4] = {OFF_V0, OFF_V1, OFF_V2, OFF_V3};

    for (int s = 0; s < 4; s++) {
        const int Ss = SS >> s;
        const int nch = Ss >> 5;
        const u16* Kb = (const u16*)(ws + koff[s]) + (size_t)bh * Ss * 64;
        const u16* Vb = (const u16*)(ws + voff[s]) + (size_t)bh * 64 * Ss;

        f16v oacc[2][2];
#pragma unroll
        for (int qt = 0; qt < 2; qt++)
#pragma unroll
            for (int ht = 0; ht < 2; ht++)
#pragma unroll
                for (int r = 0; r < 16; r++) oacc[qt][ht][r] = 0.f;
        float ls0 = 0.f, ls1 = 0.f;

        // ---- prime: chunk 0 -> buf0; prefetch chunk 1 -> regs
        uint4 kr0 = *(const uint4*)(Kb + (size_t)skey * 64 + shd8);
        uint4 kr1 = *(const uint4*)(Kb + (size_t)(skey + 16) * 64 + shd8);
        uint4 vr0 = *(const uint4*)(Vb + (size_t)svhd * Ss + svk8);
        uint4 vr1 = *(const uint4*)(Vb + (size_t)(svhd + 32) * Ss + svk8);
        *(uint4*)&Kt0[skey * 72 + shd8]        = kr0;
        *(uint4*)&Kt0[(skey + 16) * 72 + shd8] = kr1;
        *(uint4*)&Vt0[svhd * 40 + svk8]        = vr0;
        *(uint4*)&Vt0[(svhd + 32) * 40 + svk8] = vr1;
        if (nch > 1) {
            kr0 = *(const uint4*)(Kb + (size_t)(32 + skey) * 64 + shd8);
            kr1 = *(const uint4*)(Kb + (size_t)(32 + skey + 16) * 64 + shd8);
            vr0 = *(const uint4*)(Vb + (size_t)svhd * Ss + 32 + svk8);
            vr1 = *(const uint4*)(Vb + (size_t)(svhd + 32) * Ss + 32 + svk8);
        }
        __syncthreads();

        for (int c = 0; c < nch; c++) {
            u16* Ktc = (c & 1) ? Kt1 : Kt0;
            u16* Vtc = (c & 1) ? Vt1 : Vt0;
            u16* Ktn = (c & 1) ? Kt0 : Kt1;
            u16* Vtn = (c & 1) ? Vt0 : Vt1;
            // ---- QK: S^T col=q(l31), rows=key (reads buf staged >=1 chunk ago)
            f16v sa0, sa1;
#pragma unroll
            for (int r = 0; r < 16; r++) { sa0[r] = 0.f; sa1[r] = 0.f; }
#pragma unroll
            for (int ks = 0; ks < 4; ks++) {
                bf8v ka = *(const bf8v*)&Ktc[l31 * 72 + ks * 16 + half * 8];
                sa0 = __builtin_amdgcn_mfma_f32_32x32x16_bf16(ka, qf[0][ks], sa0, 0, 0, 0);
                sa1 = __builtin_amdgcn_mfma_f32_32x32x16_bf16(ka, qf[1][ks], sa1, 0, 0, 0);
            }
            // ---- exp + truncation-pack + P write; reg r=g*4+i -> key g*8+half*4+i
#pragma unroll
            for (int qt = 0; qt < 2; qt++) {
                const f16v& sa = qt ? sa1 : sa0;
                float lq = 0.f;
#pragma unroll
                for (int g = 0; g < 4; g++) {
                    float e0 = __expf(sa[g * 4 + 0]);
                    float e1 = __expf(sa[g * 4 + 1]);
                    float e2 = __expf(sa[g * 4 + 2]);
                    float e3 = __expf(sa[g * 4 + 3]);
                    lq += (e0 + e1) + (e2 + e3);
                    uint2 pk;
                    pk.x = pkt2(e0, e1);
                    pk.y = pkt2(e2, e3);
                    *(uint2*)&Pw[(qt * 32 + l31) * 40 + g * 8 + half * 4] = pk;
                }
                if (qt) ls1 += lq; else ls0 += lq;
            }
            // ---- stage chunk c+1 into the other buffer (fills P write->read gap)
            if (c + 1 < nch) {
                *(uint4*)&Ktn[skey * 72 + shd8]        = kr0;
                *(uint4*)&Ktn[(skey + 16) * 72 + shd8] = kr1;
                *(uint4*)&Vtn[svhd * 40 + svk8]        = vr0;
                *(uint4*)&Vtn[(svhd + 32) * 40 + svk8] = vr1;
            }
            // ---- prefetch chunk c+2 into regs
            if (c + 2 < nch) {
                kr0 = *(const uint4*)(Kb + (size_t)((c + 2) * 32 + skey) * 64 + shd8);
                kr1 = *(const uint4*)(Kb + (size_t)((c + 2) * 32 + skey + 16) * 64 + shd8);
                vr0 = *(const uint4*)(Vb + (size_t)svhd * Ss + (c + 2) * 32 + svk8);
                vr1 = *(const uint4*)(Vb + (size_t)(svhd + 32) * Ss + (c + 2) * 32 + svk8);
            }
            __asm__ volatile("s_waitcnt lgkmcnt(0)" ::: "memory");
            // ---- PV: O^T col=q(l31), rows=hd
#pragma unroll
            for (int kst = 0; kst < 2; kst++) {
                bf8v pb0 = *(const bf8v*)&Pw[l31 * 40 + kst * 16 + half * 8];
                bf8v pb1 = *(const bf8v*)&Pw[(32 + l31) * 40 + kst * 16 + half * 8];
#pragma unroll
                for (int ht = 0; ht < 2; ht++) {
                    bf8v va = *(const bf8v*)&Vtc[(ht * 32 + l31) * 40 + kst * 16 + half * 8];
                    oacc[0][ht] = __builtin_amdgcn_mfma_f32_32x32x16_bf16(va, pb0, oacc[0][ht], 0, 0, 0);
                    oacc[1][ht] = __builtin_amdgcn_mfma_f32_32x32x16_bf16(va, pb1, oacc[1][ht], 0, 0, 0);
                }
            }
            __syncthreads();   // buf for c+1 fully staged; everyone done reading c's buf
        }
        // ---- fold scale s (per-lane q=l31, consistent with col=q orientation)
#pragma unroll
        for (int qt = 0; qt < 2; qt++) {
            float l = qt ? ls1 : ls0;
            l += __shfl_xor(l, 32);
            float w = scw[(size_t)(b * SS + qb + qt * 32 + l31) * 4 + s] / l;
#pragma unroll
            for (int ht = 0; ht < 2; ht++)
#pragma unroll
                for (int r = 0; r < 16; r++) ofin[qt][ht][r] += w * oacc[qt][ht][r];
        }
    }
    // ---- write O: col=q=l31, hd = ht*32 + g*8 + half*4 + i (4 consecutive -> uint2)
#pragma unroll
    for (int qt = 0; qt < 2; qt++) {
        const size_t base = (size_t)(b * SS + qb + qt * 32 + l31) * 1024 + h * 64;
#pragma unroll
        for (int ht = 0; ht < 2; ht++)
#pragma unroll
            for (int g = 0; g < 4; g++) {
                uint2 pk;
                pk.x = pk2(ofin[qt][ht][g * 4 + 0], ofin[qt][ht][g * 4 + 1]);
                pk.y = pk2(ofin[qt][ht][g * 4 + 2], ofin[qt][ht][g * 4 + 3]);
                *(uint2*)&attnb[base + ht * 32 + g * 8 + half * 4] = pk;
            }
    }
}

extern "C" void kernel_launch(void* const* d_in, const int* in_sizes, int n_in,
                              void* d_out, int out_size, void* d_ws, size_t ws_size,
                              hipStream_t stream) {
    const float* x      = (const float*)d_in[0];
    const float* Wqkv   = (const float*)d_in[1];
    const float* bqkv   = (const float*)d_in[2];
    const float* Wout   = (const float*)d_in[3];
    const float* bout   = (const float*)d_in[4];
    const float* Wscale = (const float*)d_in[5];
    const float* bscale = (const float*)d_in[6];
    float* out = (float*)d_out;

    char* ws = (char*)d_ws;
    u16*   wqt   = (u16*)(ws + OFF_WQT);
    u16*   wot   = (u16*)(ws + OFF_WOT);
    u16*   xb    = (u16*)(ws + OFF_XB);
    u16*   attnb = (u16*)(ws + OFF_Q);
    float* scw   = (float*)(ws + OFF_SCW);

    xconv_kernel<<<dim3(4096), dim3(256), 0, stream>>>(x, xb);
    wconv_kernel<<<dim3(48, 16), dim3(256), 0, stream>>>(Wqkv, wqt, 3072, 1024);
    wconv_kernel<<<dim3(16, 16), dim3(256), 0, stream>>>(Wout, wot, 1024, 1024);
    scale_kernel<<<dim3(1024), dim3(256), 0, stream>>>(x, Wscale, bscale, scw);
    gemm_bt<1><<<dim3(24, 32), dim3(256), 0, stream>>>(xb, wqt, bqkv, (void*)ws, 3072, 1024);
    attn_kernel<<<dim3(16, 16, 2), dim3(128), 0, stream>>>(ws);
    gemm_bt<0><<<dim3(8, 32), dim3(256), 0, stream>>>(attnb, wot, bout, (void*)out, 1024, 1024);
}

// Round 8
// 268.933 us; speedup vs baseline: 1.6555x; 1.1051x over previous
//
#include <hip/hip_runtime.h>
#include <stdint.h>

typedef unsigned short u16;
typedef __attribute__((ext_vector_type(8))) __bf16 bf8v;    // A/B fragment: 8 bf16
typedef __attribute__((ext_vector_type(4))) float f4v;      // 16x16 C/D
typedef __attribute__((ext_vector_type(16))) float f16v;    // 32x32 C/D

#define BB 2
#define SS 2048
#define HH 1024

// workspace layout (bytes) — extent 56688640 (proven harmless in rounds 3/4/6).
#define OFF_Q   0u          // Q bf16 [4096][1024]; later attn output (same region)
#define OFF_K0  8388608u
#define OFF_K1  16777216u
#define OFF_K2  20971520u
#define OFF_K3  23068672u
#define OFF_V0  24117248u
#define OFF_V1  32505856u
#define OFF_V2  36700160u
#define OFF_V3  38797312u
#define OFF_WQT 39845888u   // Wqkv^T bf16 [3072][1024]  (6 MB)
#define OFF_WOT 46137344u   // Wout^T bf16 [1024][1024]  (2 MB)
#define OFF_XB  48234496u   // x bf16 [4096][1024]       (8 MB)
#define OFF_SCW 56623104u   // scale weights f32 [4096][4] (64 KB)

__device__ __forceinline__ u16 f2bf(float f) {
    union { float f; uint32_t u; } v; v.f = f;
    uint32_t r = v.u + 0x7fffu + ((v.u >> 16) & 1u);   // RNE
    return (u16)(r >> 16);
}
__device__ __forceinline__ uint32_t pk2(float a, float b) {
    return (uint32_t)f2bf(a) | ((uint32_t)f2bf(b) << 16);
}
// truncation pack (2 VALU): low half <- bf-trunc(a), high half <- bf-trunc(b)
__device__ __forceinline__ uint32_t pkt2(float a, float b) {
    union { float f; uint32_t u; } x, y; x.f = a; y.f = b;
    return (x.u >> 16) | (y.u & 0xffff0000u);
}

// ---------------- x f32 -> bf16 ----------------
__global__ __launch_bounds__(256) void xconv_kernel(const float* __restrict__ x,
                                                    u16* __restrict__ xb) {
    size_t t = (size_t)blockIdx.x * 256 + threadIdx.x;
    float4 v = *(const float4*)&x[t * 4];
    uint2 pk; pk.x = pk2(v.x, v.y); pk.y = pk2(v.z, v.w);
    *(uint2*)&xb[t * 4] = pk;
}

// ---------------- W f32 [K][N] -> bf16 W^T [N][K] ----------------
__global__ __launch_bounds__(256) void wconv_kernel(const float* __restrict__ W,
                                                    u16* __restrict__ Wt,
                                                    int N, int K) {
    __shared__ float tile[64][69];
    const int tid = threadIdx.x;
    const int n0 = blockIdx.x * 64, k0 = blockIdx.y * 64;
    const int r = tid >> 4, c4 = (tid & 15) * 4;
#pragma unroll
    for (int it = 0; it < 4; it++) {
        float4 v = *(const float4*)&W[(size_t)(k0 + it * 16 + r) * N + n0 + c4];
        tile[it * 16 + r][c4 + 0] = v.x; tile[it * 16 + r][c4 + 1] = v.y;
        tile[it * 16 + r][c4 + 2] = v.z; tile[it * 16 + r][c4 + 3] = v.w;
    }
    __syncthreads();
#pragma unroll
    for (int it = 0; it < 4; it++) {
        int n = it * 16 + r;
        uint2 pk;
        pk.x = pk2(tile[c4 + 0][n], tile[c4 + 1][n]);
        pk.y = pk2(tile[c4 + 2][n], tile[c4 + 3][n]);
        *(uint2*)&Wt[(size_t)(n0 + n) * K + k0 + c4] = pk;
    }
}

// ---------------- scale weights: softmax(x @ Wscale + bscale) ----------------
__global__ __launch_bounds__(256) void scale_kernel(const float* __restrict__ x,
                                                    const float* __restrict__ Wscale,
                                                    const float* __restrict__ bscale,
                                                    float* __restrict__ scw) {
    const int lane = threadIdx.x & 63;
    const int wid  = threadIdx.x >> 6;
    const int row  = blockIdx.x * 4 + wid;
    float a0 = 0.f, a1 = 0.f, a2 = 0.f, a3 = 0.f;
    for (int i = 0; i < 16; i++) {
        int hh = lane + i * 64;
        float xs = x[(size_t)row * HH + hh];
        float4 wv = *(const float4*)&Wscale[hh * 4];
        a0 += xs * wv.x; a1 += xs * wv.y; a2 += xs * wv.z; a3 += xs * wv.w;
    }
    for (int off = 1; off < 64; off <<= 1) {
        a0 += __shfl_xor(a0, off); a1 += __shfl_xor(a1, off);
        a2 += __shfl_xor(a2, off); a3 += __shfl_xor(a3, off);
    }
    if (lane == 0) {
        a0 += bscale[0]; a1 += bscale[1]; a2 += bscale[2]; a3 += bscale[3];
        float mx = fmaxf(fmaxf(a0, a1), fmaxf(a2, a3));
        float e0 = __expf(a0 - mx), e1 = __expf(a1 - mx);
        float e2 = __expf(a2 - mx), e3 = __expf(a3 - mx);
        float inv = 1.f / (e0 + e1 + e2 + e3);
        float4 o = {e0 * inv, e1 * inv, e2 * inv, e3 * inv};
        *(float4*)&scw[(size_t)row * 4] = o;
    }
}

// ---------------- bf16 MFMA GEMM, A bf16, B pre-transposed bf16 ----------------
// MODE 0: C[M,N] f32 = A@B + bias.  MODE 1: QKV scatter epilogue (K scaled by 0.125).
template<int MODE>
__global__ __launch_bounds__(256) void gemm_bt(const u16* __restrict__ A,
                                               const u16* __restrict__ Bt,
                                               const float* __restrict__ bias,
                                               void* __restrict__ Cp,
                                               int N, int K) {
    __shared__ __align__(16) u16 At[128 * 40];
    __shared__ __align__(16) u16 Btl[128 * 40];
    const int tid  = threadIdx.x;
    const int lane = tid & 63;
    const int wid  = tid >> 6;
    const int l15  = lane & 15;
    const int quad = lane >> 4;
    const int wm = wid & 1, wn = wid >> 1;
    const int m0 = blockIdx.y * 128;
    const int n0 = blockIdx.x * 128;
    const int srow = tid >> 2;           // 0..63
    const int sc8  = (tid & 3) * 8;      // 0,8,16,24

    f4v acc[4][4];
#pragma unroll
    for (int i = 0; i < 4; i++)
#pragma unroll
        for (int j = 0; j < 4; j++) acc[i][j] = (f4v){0.f, 0.f, 0.f, 0.f};

    uint4 pa0 = *(const uint4*)(A  + (size_t)(m0 + srow) * K + sc8);
    uint4 pa1 = *(const uint4*)(A  + (size_t)(m0 + srow + 64) * K + sc8);
    uint4 pb0 = *(const uint4*)(Bt + (size_t)(n0 + srow) * K + sc8);
    uint4 pb1 = *(const uint4*)(Bt + (size_t)(n0 + srow + 64) * K + sc8);

    for (int kc = 0; kc < K; kc += 32) {
        __syncthreads();
        *(uint4*)&At[srow * 40 + sc8]         = pa0;
        *(uint4*)&At[(srow + 64) * 40 + sc8]  = pa1;
        *(uint4*)&Btl[srow * 40 + sc8]        = pb0;
        *(uint4*)&Btl[(srow + 64) * 40 + sc8] = pb1;
        __syncthreads();
        if (kc + 32 < K) {
            pa0 = *(const uint4*)(A  + (size_t)(m0 + srow) * K + kc + 32 + sc8);
            pa1 = *(const uint4*)(A  + (size_t)(m0 + srow + 64) * K + kc + 32 + sc8);
            pb0 = *(const uint4*)(Bt + (size_t)(n0 + srow) * K + kc + 32 + sc8);
            pb1 = *(const uint4*)(Bt + (size_t)(n0 + srow + 64) * K + kc + 32 + sc8);
        }
        bf8v af[4], bf[4];
#pragma unroll
        for (int t = 0; t < 4; t++) {
            af[t] = *(const bf8v*)&At[(wm * 64 + t * 16 + l15) * 40 + quad * 8];
            bf[t] = *(const bf8v*)&Btl[(wn * 64 + t * 16 + l15) * 40 + quad * 8];
        }
#pragma unroll
        for (int ti = 0; ti < 4; ti++)
#pragma unroll
            for (int tj = 0; tj < 4; tj++)
                acc[ti][tj] = __builtin_amdgcn_mfma_f32_16x16x32_bf16(af[ti], bf[tj], acc[ti][tj], 0, 0, 0);
    }

    if (MODE == 0) {
#pragma unroll
        for (int ti = 0; ti < 4; ti++)
#pragma unroll
            for (int tj = 0; tj < 4; tj++)
#pragma unroll
                for (int r = 0; r < 4; r++) {
                    int m = m0 + wm * 64 + ti * 16 + quad * 4 + r;
                    int n = n0 + wn * 64 + tj * 16 + l15;
                    ((float*)Cp)[(size_t)m * N + n] = acc[ti][tj][r] + bias[n];
                }
    } else {
        char* ws = (char*)Cp;
        u16* Qd = (u16*)ws;
        u16* K0 = (u16*)(ws + OFF_K0); u16* K1 = (u16*)(ws + OFF_K1);
        u16* K2 = (u16*)(ws + OFF_K2); u16* K3 = (u16*)(ws + OFF_K3);
        u16* V0 = (u16*)(ws + OFF_V0); u16* V1 = (u16*)(ws + OFF_V1);
        u16* V2 = (u16*)(ws + OFF_V2); u16* V3 = (u16*)(ws + OFF_V3);
        const int region = n0 >> 10;
        if (region == 0) {             // ---- Q dense bf16 [tok][h*64+hd]
#pragma unroll
            for (int ti = 0; ti < 4; ti++)
#pragma unroll
                for (int tj = 0; tj < 4; tj++)
#pragma unroll
                    for (int r = 0; r < 4; r++) {
                        int m = m0 + wm * 64 + ti * 16 + quad * 4 + r;
                        int n = n0 + wn * 64 + tj * 16 + l15;
                        Qd[(size_t)m * 1024 + n] = f2bf(acc[ti][tj][r] + bias[n]);
                    }
        } else if (region == 1) {      // ---- K dilated copies, scaled by 1/sqrt(64)
#pragma unroll
            for (int ti = 0; ti < 4; ti++)
#pragma unroll
                for (int tj = 0; tj < 4; tj++) {
                    int n  = n0 + wn * 64 + tj * 16 + l15;
                    int nk = n - 1024;
                    int h = nk >> 6, hd = nk & 63;
#pragma unroll
                    for (int r = 0; r < 4; r++) {
                        int m = m0 + wm * 64 + ti * 16 + quad * 4 + r;
                        int bb = m >> 11, tok = m & 2047;
                        int bh = bb * 16 + h;
                        u16 bv = f2bf((acc[ti][tj][r] + bias[n]) * 0.125f);
                        K0[((size_t)bh * 2048 + tok) * 64 + hd] = bv;
                        if (!(r & 1)) K1[((size_t)bh * 1024 + (tok >> 1)) * 64 + hd] = bv;
                        if (r == 0) {
                            K2[((size_t)bh * 512 + (tok >> 2)) * 64 + hd] = bv;
                            if (!(quad & 1)) K3[((size_t)bh * 256 + (tok >> 3)) * 64 + hd] = bv;
                        }
                    }
                }
        } else {                       // ---- V^T dilated copies [b,h,hd,tok]
#pragma unroll
            for (int ti = 0; ti < 4; ti++)
#pragma unroll
                for (int tj = 0; tj < 4; tj++) {
                    int n  = n0 + wn * 64 + tj * 16 + l15;
                    int nv = n - 2048;
                    int h = nv >> 6, hd = nv & 63;
                    int tokb = m0 + wm * 64 + ti * 16 + quad * 4;
                    int bb = tokb >> 11, tok = tokb & 2047;
                    int bh = bb * 16 + h;
                    float v0 = acc[ti][tj][0] + bias[n];
                    float v1 = acc[ti][tj][1] + bias[n];
                    float v2 = acc[ti][tj][2] + bias[n];
                    float v3 = acc[ti][tj][3] + bias[n];
                    u16 c0 = f2bf(v0), c1 = f2bf(v1), c2 = f2bf(v2), c3 = f2bf(v3);
                    uint2 pk;
                    pk.x = (uint32_t)c0 | ((uint32_t)c1 << 16);
                    pk.y = (uint32_t)c2 | ((uint32_t)c3 << 16);
                    *(uint2*)&V0[((size_t)bh * 64 + hd) * 2048 + tok] = pk;
                    *(uint32_t*)&V1[((size_t)bh * 64 + hd) * 1024 + (tok >> 1)] =
                        (uint32_t)c0 | ((uint32_t)c2 << 16);
                    V2[((size_t)bh * 64 + hd) * 512 + (tok >> 2)] = c0;
                    if (!(quad & 1)) V3[((size_t)bh * 64 + hd) * 256 + (tok >> 3)] = c0;
                }
        }
    }
}

// ---------------- multi-scale attention, 32x32x16 MFMA, 4 waves x 32q ----------------
// block = 256 threads = 4 waves, each wave owns 32 q. Per-wave regs ~130 ->
// 2 waves/SIMD occupancy (round-6 lesson: shrink the wave, don't cap registers).
// K/V staged cooperatively (256 thr: 1 uint4 + 1 ds_write each for K and V),
// double-buffered, 1 barrier/chunk. Round-5-verified orientation:
// S^T = K.Q^T (col=q=l31); P [q][key] wave-private; O^T = V.P^T (col=q=l31).
__global__ void attn_kernel(const char* __restrict__ ws) {
    __shared__ __align__(16) u16 smem[14848];   // Kt 2x2304 | Vt 2x2560 | P 4x1280
    u16* Kt0 = smem;            // [32 key][72]
    u16* Kt1 = smem + 2304;
    u16* Vt0 = smem + 4608;     // [64 hd][40]
    u16* Vt1 = smem + 7168;
    u16* Pt  = smem + 9728;     // per-wave [32 q][40]

    const u16* Qd    = (const u16*)(ws + OFF_Q);
    const float* scw = (const float*)(ws + OFF_SCW);
    u16* attnb       = (u16*)(ws + OFF_Q);          // aliases Q (block reads Q first)

    const int tid  = threadIdx.x;
    const int lane = tid & 63;
    const int wid  = tid >> 6;
    const int l31  = lane & 31;
    const int half = lane >> 5;
    const int b = blockIdx.z, h = blockIdx.y;
    const int q  = blockIdx.x * 128 + wid * 32 + l31;   // this lane's token
    const int bh = b * 16 + h;

    // cooperative staging coords (256 threads)
    const int skey = tid >> 3;             // 0..31
    const int shd8 = (tid & 7) * 8;
    const int svhd = tid >> 2;             // 0..63
    const int svk8 = (tid & 3) * 8;

    // Q B-frags: qf[ks] = Q[q][h*64 + ks*16 + half*8 + j]
    bf8v qf[4];
#pragma unroll
    for (int ks = 0; ks < 4; ks++)
        qf[ks] = *(const bf8v*)(Qd + (size_t)(b * SS + q) * 1024 + h * 64 + ks * 16 + half * 8);

    u16* Pw = Pt + wid * 1280;

    f16v ofin[2];
#pragma unroll
    for (int ht = 0; ht < 2; ht++)
#pragma unroll
        for (int r = 0; r < 16; r++) ofin[ht][r] = 0.f;

    const uint32_t koff[4] = {OFF_K0, OFF_K1, OFF_K2, OFF_K3};
    const uint32_t voff[4] = {OFF_V0, OFF_V1, OFF_V2, OFF_V3};

    for (int s = 0; s < 4; s++) {
        const int Ss = SS >> s;
        const int nch = Ss >> 5;
        const u16* Kb = (const u16*)(ws + koff[s]) + (size_t)bh * Ss * 64;
        const u16* Vb = (const u16*)(ws + voff[s]) + (size_t)bh * 64 * Ss;

        f16v oacc[2];
#pragma unroll
        for (int ht = 0; ht < 2; ht++)
#pragma unroll
            for (int r = 0; r < 16; r++) oacc[ht][r] = 0.f;
        float ls = 0.f;

        // ---- prime: chunk 0 -> buf0; prefetch chunk 1 -> regs
        uint4 kr = *(const uint4*)(Kb + (size_t)skey * 64 + shd8);
        uint4 vr = *(const uint4*)(Vb + (size_t)svhd * Ss + svk8);
        *(uint4*)&Kt0[skey * 72 + shd8] = kr;
        *(uint4*)&Vt0[svhd * 40 + svk8] = vr;
        if (nch > 1) {
            kr = *(const uint4*)(Kb + (size_t)(32 + skey) * 64 + shd8);
            vr = *(const uint4*)(Vb + (size_t)svhd * Ss + 32 + svk8);
        }
        __syncthreads();

        for (int c = 0; c < nch; c++) {
            u16* Ktc = (c & 1) ? Kt1 : Kt0;
            u16* Vtc = (c & 1) ? Vt1 : Vt0;
            u16* Ktn = (c & 1) ? Kt0 : Kt1;
            u16* Vtn = (c & 1) ? Vt0 : Vt1;
            // ---- QK: S^T col=q(l31), rows=key
            f16v sa;
#pragma unroll
            for (int r = 0; r < 16; r++) sa[r] = 0.f;
#pragma unroll
            for (int ks = 0; ks < 4; ks++) {
                bf8v ka = *(const bf8v*)&Ktc[l31 * 72 + ks * 16 + half * 8];
                sa = __builtin_amdgcn_mfma_f32_32x32x16_bf16(ka, qf[ks], sa, 0, 0, 0);
            }
            // ---- exp + truncation-pack + P write; reg r=g*4+i -> key g*8+half*4+i
#pragma unroll
            for (int g = 0; g < 4; g++) {
                float e0 = __expf(sa[g * 4 + 0]);
                float e1 = __expf(sa[g * 4 + 1]);
                float e2 = __expf(sa[g * 4 + 2]);
                float e3 = __expf(sa[g * 4 + 3]);
                ls += (e0 + e1) + (e2 + e3);
                uint2 pk;
                pk.x = pkt2(e0, e1);
                pk.y = pkt2(e2, e3);
                *(uint2*)&Pw[l31 * 40 + g * 8 + half * 4] = pk;
            }
            // ---- stage chunk c+1 into the other buffer (fills P write->read gap)
            if (c + 1 < nch) {
                *(uint4*)&Ktn[skey * 72 + shd8] = kr;
                *(uint4*)&Vtn[svhd * 40 + svk8] = vr;
            }
            // ---- prefetch chunk c+2 into regs
            if (c + 2 < nch) {
                kr = *(const uint4*)(Kb + (size_t)((c + 2) * 32 + skey) * 64 + shd8);
                vr = *(const uint4*)(Vb + (size_t)svhd * Ss + (c + 2) * 32 + svk8);
            }
            __asm__ volatile("s_waitcnt lgkmcnt(0)" ::: "memory");
            // ---- PV: O^T col=q(l31), rows=hd
#pragma unroll
            for (int kst = 0; kst < 2; kst++) {
                bf8v pb = *(const bf8v*)&Pw[l31 * 40 + kst * 16 + half * 8];
#pragma unroll
                for (int ht = 0; ht < 2; ht++) {
                    bf8v va = *(const bf8v*)&Vtc[(ht * 32 + l31) * 40 + kst * 16 + half * 8];
                    oacc[ht] = __builtin_amdgcn_mfma_f32_32x32x16_bf16(va, pb, oacc[ht], 0, 0, 0);
                }
            }
            __syncthreads();   // buf for c+1 fully staged; everyone done reading c's buf
        }
        // ---- fold scale s (per-lane q=l31, consistent with col=q orientation)
        ls += __shfl_xor(ls, 32);
        float w = scw[(size_t)(b * SS + q) * 4 + s] / ls;
#pragma unroll
        for (int ht = 0; ht < 2; ht++)
#pragma unroll
            for (int r = 0; r < 16; r++) ofin[ht][r] += w * oacc[ht][r];
    }
    // ---- write O: col=q=l31, hd = ht*32 + g*8 + half*4 + i (4 consecutive -> uint2)
    const size_t base = (size_t)(b * SS + q) * 1024 + h * 64;
#pragma unroll
    for (int ht = 0; ht < 2; ht++)
#pragma unroll
        for (int g = 0; g < 4; g++) {
            uint2 pk;
            pk.x = pk2(ofin[ht][g * 4 + 0], ofin[ht][g * 4 + 1]);
            pk.y = pk2(ofin[ht][g * 4 + 2], ofin[ht][g * 4 + 3]);
            *(uint2*)&attnb[base + ht * 32 + g * 8 + half * 4] = pk;
        }
}

extern "C" void kernel_launch(void* const* d_in, const int* in_sizes, int n_in,
                              void* d_out, int out_size, void* d_ws, size_t ws_size,
                              hipStream_t stream) {
    const float* x      = (const float*)d_in[0];
    const float* Wqkv   = (const float*)d_in[1];
    const float* bqkv   = (const float*)d_in[2];
    const float* Wout   = (const float*)d_in[3];
    const float* bout   = (const float*)d_in[4];
    const float* Wscale = (const float*)d_in[5];
    const float* bscale = (const float*)d_in[6];
    float* out = (float*)d_out;

    char* ws = (char*)d_ws;
    u16*   wqt   = (u16*)(ws + OFF_WQT);
    u16*   wot   = (u16*)(ws + OFF_WOT);
    u16*   xb    = (u16*)(ws + OFF_XB);
    u16*   attnb = (u16*)(ws + OFF_Q);
    float* scw   = (float*)(ws + OFF_SCW);

    xconv_kernel<<<dim3(4096), dim3(256), 0, stream>>>(x, xb);
    wconv_kernel<<<dim3(48, 16), dim3(256), 0, stream>>>(Wqkv, wqt, 3072, 1024);
    wconv_kernel<<<dim3(16, 16), dim3(256), 0, stream>>>(Wout, wot, 1024, 1024);
    scale_kernel<<<dim3(1024), dim3(256), 0, stream>>>(x, Wscale, bscale, scw);
    gemm_bt<1><<<dim3(24, 32), dim3(256), 0, stream>>>(xb, wqt, bqkv, (void*)ws, 3072, 1024);
    attn_kernel<<<dim3(16, 16, 2), dim3(256), 0, stream>>>(ws);
    gemm_bt<0><<<dim3(8, 32), dim3(256), 0, stream>>>(attnb, wot, bout, (void*)out, 1024, 1024);
}